// Round 2
// baseline (583.225 us; speedup 1.0000x reference)
//
#include <hip/hip_runtime.h>
#include <math.h>

namespace {
constexpr int IH = 224, IW = 224;
constexpr int H2 = 67, W2 = 67;
constexpr int MH = 56, MW = 56;
constexpr int CI = 3, CM = 21;
constexpr int ND = 6;
constexpr int K = 48;
constexpr int HW = IH * IW;    // 50176
constexpr int HW2 = H2 * W2;   // 4489
constexpr float EPS = 1e-8f;
__device__ __constant__ int DILS_C[ND] = {1, 2, 4, 8, 12, 24};
}

struct PosArr { float v[K]; };

// ---------------- bilinear downsample imgs 224->67 (align_corners) ----------
__global__ void k_img_down(const float* __restrict__ img, float* __restrict__ img2) {
    int t = blockIdx.x * blockDim.x + threadIdx.x;
    if (t >= CI * HW2) return;
    int c = t / HW2, r = t % HW2;
    int y = r / W2, x = r % W2;
    float fy = (float)y * ((float)(IH - 1) / (float)(H2 - 1));
    float fx = (float)x * ((float)(IW - 1) / (float)(W2 - 1));
    int y0 = (int)floorf(fy); int y1 = min(y0 + 1, IH - 1); float wy = fy - (float)y0;
    int x0 = (int)floorf(fx); int x1 = min(x0 + 1, IW - 1); float wx = fx - (float)x0;
    const float* p = img + c * HW;
    float v00 = p[y0 * IW + x0], v01 = p[y0 * IW + x1];
    float v10 = p[y1 * IW + x0], v11 = p[y1 * IW + x1];
    float r0 = v00 * (1.f - wy) + v10 * wy;
    float r1 = v01 * (1.f - wy) + v11 * wy;
    img2[t] = r0 * (1.f - wx) + r1 * wx;
}

// ---------------- low-res affinity: 16 lanes per (pixel,channel) ------------
// aff2 accumulates sum over channels of (|n-center|/std)^2 via atomicAdd.
// (negative sign and /CI applied when read in k_aff_total)
__global__ void k_aff2(const float* __restrict__ img2, float* __restrict__ aff2) {
    int gtid = blockIdx.x * blockDim.x + threadIdx.x;
    int grp = gtid >> 4;          // (pixel, channel) group
    int lane = gtid & 15;         // k = lane, lane+16, lane+32
    if (grp >= CI * HW2) return;
    int c = grp / HW2, t = grp % HW2;
    int y = t / W2, x = t % W2;
    const float* p = img2 + c * HW2;
    float center = p[y * W2 + x];

    const int KI[8] = {0, 0, 0, 1, 1, 2, 2, 2};
    const int KJ[8] = {0, 1, 2, 0, 2, 0, 1, 2};

    float v[3];
    int kk[3];
    #pragma unroll
    for (int s = 0; s < 3; ++s) {
        int k = lane + 16 * s;
        kk[s] = k;
        int di = k >> 3, o = k & 7;
        int d = DILS_C[di];
        int ym = max(y - d, 0), yp = min(y + d, H2 - 1);
        int xm = max(x - d, 0), xp = min(x + d, W2 - 1);
        int rows[3] = {ym, y, yp};
        int cols[3] = {xm, x, xp};
        v[s] = p[rows[KI[o]] * W2 + cols[KJ[o]]];
    }

    float sum = v[0] + v[1] + v[2];
    #pragma unroll
    for (int off = 1; off < 16; off <<= 1)
        sum += __shfl_xor(sum, off, 16);
    float mean = sum * (1.f / (float)K);

    float ssl = 0.f;
    #pragma unroll
    for (int s = 0; s < 3; ++s) { float dd = v[s] - mean; ssl += dd * dd; }
    #pragma unroll
    for (int off = 1; off < 16; off <<= 1)
        ssl += __shfl_xor(ssl, off, 16);
    float stdv = sqrtf(ssl * (1.f / (float)(K - 1)));
    float inv = 1.f / (stdv + EPS);

    #pragma unroll
    for (int s = 0; s < 3; ++s) {
        float tt = fabsf(v[s] - center) * inv;
        atomicAdd(&aff2[kk[s] * HW2 + t], tt * tt);
    }
}

// ---------------- full-res aff + upsampled aff2 + pos -> aff_total ----------
// writes afft TRANSPOSED: afft[t*K + k]
__global__ void k_aff_total(const float* __restrict__ img,
                            const float* __restrict__ aff2,
                            float* __restrict__ afft, PosArr pos) {
    int t = blockIdx.x * blockDim.x + threadIdx.x;
    if (t >= HW) return;
    int y = t / IW, x = t % IW;

    float av[K];
    #pragma unroll
    for (int k = 0; k < K; ++k) av[k] = 0.f;

    for (int c = 0; c < CI; ++c) {
        const float* p = img + c * HW;
        float center = p[y * IW + x];
        float nv[K];
        float sum = 0.f;
        const int DILS[ND] = {1, 2, 4, 8, 12, 24};
        #pragma unroll
        for (int di = 0; di < ND; ++di) {
            int d = DILS[di];
            int ym = max(y - d, 0), yp = min(y + d, IH - 1);
            int xm = max(x - d, 0), xp = min(x + d, IW - 1);
            int rows[3] = {ym, y, yp};
            int cols[3] = {xm, x, xp};
            const int KI[8] = {0, 0, 0, 1, 1, 2, 2, 2};
            const int KJ[8] = {0, 1, 2, 0, 2, 0, 1, 2};
            #pragma unroll
            for (int o = 0; o < 8; ++o) {
                float v = p[rows[KI[o]] * IW + cols[KJ[o]]];
                nv[di * 8 + o] = v;
                sum += v;
            }
        }
        float mean = sum * (1.f / (float)K);
        float ss = 0.f;
        #pragma unroll
        for (int k = 0; k < K; ++k) { float dd = nv[k] - mean; ss += dd * dd; }
        float stdv = sqrtf(ss * (1.f / (float)(K - 1)));
        float inv = 1.f / (stdv + EPS);
        #pragma unroll
        for (int k = 0; k < K; ++k) { float tt = fabsf(nv[k] - center) * inv; av[k] += tt * tt; }
    }

    // aff = -(mean over c) / W1^2 ; then softmax over k
    const float sc = -(1.f / (float)CI) / (0.3f * 0.3f);
    float m1 = -INFINITY;
    #pragma unroll
    for (int k = 0; k < K; ++k) { av[k] *= sc; m1 = fmaxf(m1, av[k]); }
    float e1 = 0.f;
    #pragma unroll
    for (int k = 0; k < K; ++k) { av[k] = expf(av[k] - m1); e1 += av[k]; }
    float r1 = 1.f / e1;

    // bilinear sample of aff2 (67x67 -> 224x224, align_corners), then softmax
    float fy = (float)y * ((float)(H2 - 1) / (float)(IH - 1));
    float fx = (float)x * ((float)(W2 - 1) / (float)(IW - 1));
    int y0 = (int)floorf(fy); int y1 = min(y0 + 1, H2 - 1); float wy = fy - (float)y0;
    int x0 = (int)floorf(fx); int x1 = min(x0 + 1, W2 - 1); float wx = fx - (float)x0;
    int i00 = y0 * W2 + x0, i01 = y0 * W2 + x1, i10 = y1 * W2 + x0, i11 = y1 * W2 + x1;
    float w00 = (1.f - wy) * (1.f - wx), w01 = (1.f - wy) * wx;
    float w10 = wy * (1.f - wx), w11 = wy * wx;

    const float sc2 = -(1.f / (float)CI);   // fold sign + channel mean of aff2
    float a2[K];
    float m2 = -INFINITY;
    #pragma unroll
    for (int k = 0; k < K; ++k) {
        const float* q = aff2 + k * HW2;
        float v = (q[i00] * w00 + q[i01] * w01 + q[i10] * w10 + q[i11] * w11) * sc2;
        a2[k] = v;
        m2 = fmaxf(m2, v);
    }
    float e2 = 0.f;
    #pragma unroll
    for (int k = 0; k < K; ++k) { a2[k] = expf(a2[k] - m2); e2 += a2[k]; }
    float r2 = 1.f / e2;

    float* o = afft + (size_t)t * K;
    #pragma unroll
    for (int k = 0; k < K; ++k)
        o[k] = av[k] * r1 + a2[k] * r2 + pos.v[k];
}

// ---------------- mask upsample 56 -> 224 -----------------------------------
__global__ void k_mask_up(const float* __restrict__ m, float* __restrict__ mu) {
    int t = blockIdx.x * blockDim.x + threadIdx.x;
    if (t >= CM * HW) return;
    int c = t / HW, r = t % HW;
    int y = r / IW, x = r % IW;
    float fy = (float)y * ((float)(MH - 1) / (float)(IH - 1));
    float fx = (float)x * ((float)(MW - 1) / (float)(IW - 1));
    int y0 = (int)floorf(fy); int y1 = min(y0 + 1, MH - 1); float wy = fy - (float)y0;
    int x0 = (int)floorf(fx); int x1 = min(x0 + 1, MW - 1); float wx = fx - (float)x0;
    const float* p = m + c * MH * MW;
    float v00 = p[y0 * MW + x0], v01 = p[y0 * MW + x1];
    float v10 = p[y1 * MW + x0], v11 = p[y1 * MW + x1];
    float r0 = v00 * (1.f - wy) + v10 * wy;
    float r1 = v01 * (1.f - wy) + v11 * wy;
    mu[t] = r0 * (1.f - wx) + r1 * wx;
}

// ---------------- one propagation iteration ---------------------------------
// thread = (pixel, channel-group of 3); afft is [HW][K]
__global__ void k_prop(const float* __restrict__ min_,
                       const float* __restrict__ afft,
                       float* __restrict__ mout) {
    int gid = blockIdx.x * blockDim.x + threadIdx.x;
    if (gid >= (CM / 3) * HW) return;
    int t = gid % HW;
    int c0 = (gid / HW) * 3;
    int y = t / IW, x = t % IW;

    // 48 affinity weights: 12 float4 loads (afft + t*48 is 192B-aligned)
    float a[K];
    {
        const float4* af = reinterpret_cast<const float4*>(afft + (size_t)t * K);
        #pragma unroll
        for (int i = 0; i < 12; ++i) {
            float4 v = af[i];
            a[4 * i + 0] = v.x; a[4 * i + 1] = v.y;
            a[4 * i + 2] = v.z; a[4 * i + 3] = v.w;
        }
    }

    // clamped row/col offsets shared across the 3 channels
    const int DILS[ND] = {1, 2, 4, 8, 12, 24};
    int rm[ND], rp[ND], cm[ND], cp[ND];
    #pragma unroll
    for (int di = 0; di < ND; ++di) {
        int d = DILS[di];
        rm[di] = max(y - d, 0) * IW;
        rp[di] = min(y + d, IH - 1) * IW;
        cm[di] = max(x - d, 0);
        cp[di] = min(x + d, IW - 1);
    }
    int yc = y * IW;

    float acc0 = 0.f, acc1 = 0.f, acc2 = 0.f;
    #pragma unroll
    for (int cc = 0; cc < 3; ++cc) {
        const float* p = min_ + (size_t)(c0 + cc) * HW;
        float acc = 0.f;
        #pragma unroll
        for (int di = 0; di < ND; ++di) {
            int kb = di * 8;
            acc += p[rm[di] + cm[di]] * a[kb + 0];
            acc += p[rm[di] + x     ] * a[kb + 1];
            acc += p[rm[di] + cp[di]] * a[kb + 2];
            acc += p[yc     + cm[di]] * a[kb + 3];
            acc += p[yc     + cp[di]] * a[kb + 4];
            acc += p[rp[di] + cm[di]] * a[kb + 5];
            acc += p[rp[di] + x     ] * a[kb + 6];
            acc += p[rp[di] + cp[di]] * a[kb + 7];
        }
        if (cc == 0) acc0 = acc; else if (cc == 1) acc1 = acc; else acc2 = acc;
    }
    mout[(size_t)(c0 + 0) * HW + t] = acc0;
    mout[(size_t)(c0 + 1) * HW + t] = acc1;
    mout[(size_t)(c0 + 2) * HW + t] = acc2;
}

extern "C" void kernel_launch(void* const* d_in, const int* in_sizes, int n_in,
                              void* d_out, int out_size, void* d_ws, size_t ws_size,
                              hipStream_t stream) {
    const float* imgs  = (const float*)d_in[0];
    const float* masks = (const float*)d_in[1];
    float* out = (float*)d_out;

    float* ws = (float*)d_ws;
    float* imgs2 = ws;                       // CI*HW2 = 13467 -> pad to 16384
    float* aff2  = imgs2 + 16384;            // K*HW2  = 215472
    float* afft  = aff2 + K * HW2;           // K*HW   = 2408448 (layout [HW][K])
    float* mA    = afft + (size_t)K * HW;    // CM*HW  = 1053696
    float* mB    = mA + (size_t)CM * HW;     // CM*HW  = 1053696

    // host-side positional softmax (input-independent, same every call)
    PosArr pos;
    {
        double pv[K];
        const int dil[ND] = {1, 2, 4, 8, 12, 24};
        const double s2 = sqrt(2.0);
        for (int di = 0; di < ND; ++di)
            for (int o = 0; o < 8; ++o) {
                double base = (o == 0 || o == 2 || o == 5 || o == 7) ? s2 : 1.0;
                pv[di * 8 + o] = base * (double)dil[di];
            }
        double sum = 0.0; for (int k = 0; k < K; ++k) sum += pv[k];
        double mean = sum / K;
        double ssd = 0.0; for (int k = 0; k < K; ++k) { double d0 = pv[k] - mean; ssd += d0 * d0; }
        double stdv = sqrt(ssd / (K - 1));
        double pa[K];
        double mx = -1e300;
        for (int k = 0; k < K; ++k) {
            double u = pv[k] / (stdv + 1e-8) / 0.3;
            pa[k] = -u * u;
            if (pa[k] > mx) mx = pa[k];
        }
        double es = 0.0, ev[K];
        for (int k = 0; k < K; ++k) { ev[k] = exp(pa[k] - mx); es += ev[k]; }
        for (int k = 0; k < K; ++k) pos.v[k] = (float)(ev[k] / es);
    }

    dim3 blk(256);
    hipMemsetAsync(aff2, 0, (size_t)K * HW2 * sizeof(float), stream);
    k_img_down<<<(CI * HW2 + 255) / 256, blk, 0, stream>>>(imgs, imgs2);
    k_aff2<<<(CI * HW2 * 16 + 255) / 256, blk, 0, stream>>>(imgs2, aff2);
    k_aff_total<<<(HW + 255) / 256, blk, 0, stream>>>(imgs, aff2, afft, pos);
    k_mask_up<<<(CM * HW + 255) / 256, blk, 0, stream>>>(masks, mA);

    float* bufs[2] = {mA, mB};
    const float* cur = mA;
    const int nprop_threads = (CM / 3) * HW;   // 351232
    for (int i = 0; i < 10; ++i) {
        float* o = (i == 9) ? out : bufs[(i + 1) & 1];
        k_prop<<<(nprop_threads + 255) / 256, blk, 0, stream>>>(cur, afft, o);
        cur = o;
    }
}

// Round 3
// 315.474 us; speedup vs baseline: 1.8487x; 1.8487x over previous
//
#include <hip/hip_runtime.h>
#include <math.h>

namespace {
constexpr int IH = 224, IW = 224;
constexpr int H2 = 67, W2 = 67;
constexpr int MH = 56, MW = 56;
constexpr int CI = 3, CM = 21;
constexpr int ND = 6;
constexpr int K = 48;
constexpr int HW = IH * IW;    // 50176
constexpr int HW2 = H2 * W2;   // 4489
constexpr float EPS = 1e-8f;
constexpr int PROP_TILES = HW / 64;          // 784 tiles of 64 px
constexpr int TILES_PER_XCD = PROP_TILES / 8; // 98
__device__ __constant__ int DILS_C[ND] = {1, 2, 4, 8, 12, 24};
}

struct PosArr { float v[K]; };

// ---------------- bilinear downsample imgs 224->67 (align_corners) ----------
__global__ void k_img_down(const float* __restrict__ img, float* __restrict__ img2) {
    int t = blockIdx.x * blockDim.x + threadIdx.x;
    if (t >= CI * HW2) return;
    int c = t / HW2, r = t % HW2;
    int y = r / W2, x = r % W2;
    float fy = (float)y * ((float)(IH - 1) / (float)(H2 - 1));
    float fx = (float)x * ((float)(IW - 1) / (float)(W2 - 1));
    int y0 = (int)floorf(fy); int y1 = min(y0 + 1, IH - 1); float wy = fy - (float)y0;
    int x0 = (int)floorf(fx); int x1 = min(x0 + 1, IW - 1); float wx = fx - (float)x0;
    const float* p = img + c * HW;
    float v00 = p[y0 * IW + x0], v01 = p[y0 * IW + x1];
    float v10 = p[y1 * IW + x0], v11 = p[y1 * IW + x1];
    float r0 = v00 * (1.f - wy) + v10 * wy;
    float r1 = v01 * (1.f - wy) + v11 * wy;
    img2[t] = r0 * (1.f - wx) + r1 * wx;
}

// ---------------- low-res affinity: one WAVE per pixel ----------------------
// aff2 layout [HW2][K]; stores sum over channels of (|n-center|/std)^2
// (negative sign and /CI applied when read in k_aff_total)
__global__ void k_aff2(const float* __restrict__ img2, float* __restrict__ aff2) {
    int gtid = blockIdx.x * blockDim.x + threadIdx.x;
    int wave = gtid >> 6;
    int lane = threadIdx.x & 63;
    if (wave >= HW2) return;
    int t = wave;
    int y = t / W2, x = t % W2;

    int k = (lane < K) ? lane : (K - 1);
    int di = k >> 3, o = k & 7;
    int d = DILS_C[di];
    int ym = max(y - d, 0), yp = min(y + d, H2 - 1);
    int xm = max(x - d, 0), xp = min(x + d, W2 - 1);
    const int KI[8] = {0, 0, 0, 1, 1, 2, 2, 2};
    const int KJ[8] = {0, 1, 2, 0, 2, 0, 1, 2};
    int rows[3] = {ym, y, yp};
    int cols[3] = {xm, x, xp};
    int nidx = rows[KI[o]] * W2 + cols[KJ[o]];

    float av = 0.f;
    #pragma unroll
    for (int c = 0; c < CI; ++c) {
        const float* p = img2 + c * HW2;
        float center = p[y * W2 + x];
        float v = p[nidx];
        float vv = (lane < K) ? v : 0.f;
        float s = vv, s2 = vv * vv;
        #pragma unroll
        for (int off = 1; off < 64; off <<= 1) {
            s  += __shfl_xor(s, off);
            s2 += __shfl_xor(s2, off);
        }
        float mean = s * (1.f / (float)K);
        float ss = s2 - (float)K * mean * mean;
        float stdv = sqrtf(fmaxf(ss, 0.f) * (1.f / (float)(K - 1)));
        float inv = 1.f / (stdv + EPS);
        float tt = fabsf(v - center) * inv;
        av += tt * tt;
    }
    if (lane < K) aff2[(size_t)t * K + k] = av;
}

// ---------------- full-res aff + upsampled aff2 + pos -> aff_total ----------
// aff2 layout [HW2][K]; writes afft TRANSPOSED: afft[t*K + k]
__global__ void k_aff_total(const float* __restrict__ img,
                            const float* __restrict__ aff2,
                            float* __restrict__ afft, PosArr pos) {
    int t = blockIdx.x * blockDim.x + threadIdx.x;
    if (t >= HW) return;
    int y = t / IW, x = t % IW;

    float av[K];
    #pragma unroll
    for (int k = 0; k < K; ++k) av[k] = 0.f;

    for (int c = 0; c < CI; ++c) {
        const float* p = img + c * HW;
        float center = p[y * IW + x];
        float nv[K];
        float sum = 0.f;
        const int DILS[ND] = {1, 2, 4, 8, 12, 24};
        #pragma unroll
        for (int di = 0; di < ND; ++di) {
            int d = DILS[di];
            int ym = max(y - d, 0), yp = min(y + d, IH - 1);
            int xm = max(x - d, 0), xp = min(x + d, IW - 1);
            int rows[3] = {ym, y, yp};
            int cols[3] = {xm, x, xp};
            const int KI[8] = {0, 0, 0, 1, 1, 2, 2, 2};
            const int KJ[8] = {0, 1, 2, 0, 2, 0, 1, 2};
            #pragma unroll
            for (int o = 0; o < 8; ++o) {
                float v = p[rows[KI[o]] * IW + cols[KJ[o]]];
                nv[di * 8 + o] = v;
                sum += v;
            }
        }
        float mean = sum * (1.f / (float)K);
        float ss = 0.f;
        #pragma unroll
        for (int k = 0; k < K; ++k) { float dd = nv[k] - mean; ss += dd * dd; }
        float stdv = sqrtf(ss * (1.f / (float)(K - 1)));
        float inv = 1.f / (stdv + EPS);
        #pragma unroll
        for (int k = 0; k < K; ++k) { float tt = fabsf(nv[k] - center) * inv; av[k] += tt * tt; }
    }

    // aff = -(mean over c) / W1^2 ; then softmax over k
    const float sc = -(1.f / (float)CI) / (0.3f * 0.3f);
    float m1 = -INFINITY;
    #pragma unroll
    for (int k = 0; k < K; ++k) { av[k] *= sc; m1 = fmaxf(m1, av[k]); }
    float e1 = 0.f;
    #pragma unroll
    for (int k = 0; k < K; ++k) { av[k] = expf(av[k] - m1); e1 += av[k]; }
    float r1 = 1.f / e1;

    // bilinear sample of aff2 (67x67 -> 224x224, align_corners), then softmax
    float fy = (float)y * ((float)(H2 - 1) / (float)(IH - 1));
    float fx = (float)x * ((float)(W2 - 1) / (float)(IW - 1));
    int y0 = (int)floorf(fy); int y1 = min(y0 + 1, H2 - 1); float wy = fy - (float)y0;
    int x0 = (int)floorf(fx); int x1 = min(x0 + 1, W2 - 1); float wx = fx - (float)x0;
    const float* q00 = aff2 + (size_t)(y0 * W2 + x0) * K;
    const float* q01 = aff2 + (size_t)(y0 * W2 + x1) * K;
    const float* q10 = aff2 + (size_t)(y1 * W2 + x0) * K;
    const float* q11 = aff2 + (size_t)(y1 * W2 + x1) * K;
    float w00 = (1.f - wy) * (1.f - wx), w01 = (1.f - wy) * wx;
    float w10 = wy * (1.f - wx), w11 = wy * wx;

    const float sc2 = -(1.f / (float)CI);   // fold sign + channel mean of aff2
    float a2[K];
    float m2 = -INFINITY;
    #pragma unroll
    for (int k = 0; k < K; ++k) {
        float v = (q00[k] * w00 + q01[k] * w01 + q10[k] * w10 + q11[k] * w11) * sc2;
        a2[k] = v;
        m2 = fmaxf(m2, v);
    }
    float e2 = 0.f;
    #pragma unroll
    for (int k = 0; k < K; ++k) { a2[k] = expf(a2[k] - m2); e2 += a2[k]; }
    float r2 = 1.f / e2;

    float* o = afft + (size_t)t * K;
    #pragma unroll
    for (int k = 0; k < K; ++k)
        o[k] = av[k] * r1 + a2[k] * r2 + pos.v[k];
}

// ---------------- mask upsample 56 -> 224 -----------------------------------
__global__ void k_mask_up(const float* __restrict__ m, float* __restrict__ mu) {
    int t = blockIdx.x * blockDim.x + threadIdx.x;
    if (t >= CM * HW) return;
    int c = t / HW, r = t % HW;
    int y = r / IW, x = r % IW;
    float fy = (float)y * ((float)(MH - 1) / (float)(IH - 1));
    float fx = (float)x * ((float)(MW - 1) / (float)(IW - 1));
    int y0 = (int)floorf(fy); int y1 = min(y0 + 1, MH - 1); float wy = fy - (float)y0;
    int x0 = (int)floorf(fx); int x1 = min(x0 + 1, MW - 1); float wx = fx - (float)x0;
    const float* p = m + c * MH * MW;
    float v00 = p[y0 * MW + x0], v01 = p[y0 * MW + x1];
    float v10 = p[y1 * MW + x0], v11 = p[y1 * MW + x1];
    float r0 = v00 * (1.f - wy) + v10 * wy;
    float r1 = v01 * (1.f - wy) + v11 * wy;
    mu[t] = r0 * (1.f - wx) + r1 * wx;
}

// ---------------- one propagation iteration ---------------------------------
// Block = 448 threads = 7 waves; each wave = one 3-channel group, all waves
// share the same 64-pixel tile (afft tile hits in L1 across the 7 waves).
// afft layout [HW][K].
__global__ __launch_bounds__(448) void k_prop(const float* __restrict__ min_,
                                              const float* __restrict__ afft,
                                              float* __restrict__ mout) {
    int w = threadIdx.x >> 6;          // 0..6 -> channel group
    int lane = threadIdx.x & 63;
    // bijective XCD swizzle: 784 tiles = 8 XCDs x 98 contiguous tiles
    int bid = blockIdx.x;
    int tile = (bid & 7) * TILES_PER_XCD + (bid >> 3);
    int t = tile * 64 + lane;
    int c0 = w * 3;
    int y = t / IW, x = t % IW;

    // 48 affinity weights: 12 float4 loads (afft + t*48 is 16B-aligned)
    float a[K];
    {
        const float4* af = reinterpret_cast<const float4*>(afft + (size_t)t * K);
        #pragma unroll
        for (int i = 0; i < 12; ++i) {
            float4 v = af[i];
            a[4 * i + 0] = v.x; a[4 * i + 1] = v.y;
            a[4 * i + 2] = v.z; a[4 * i + 3] = v.w;
        }
    }

    // clamped row/col offsets shared across the 3 channels
    const int DILS[ND] = {1, 2, 4, 8, 12, 24};
    int rm[ND], rp[ND], cm[ND], cp[ND];
    #pragma unroll
    for (int di = 0; di < ND; ++di) {
        int d = DILS[di];
        rm[di] = max(y - d, 0) * IW;
        rp[di] = min(y + d, IH - 1) * IW;
        cm[di] = max(x - d, 0);
        cp[di] = min(x + d, IW - 1);
    }
    int yc = y * IW;

    float acc0 = 0.f, acc1 = 0.f, acc2 = 0.f;
    #pragma unroll
    for (int cc = 0; cc < 3; ++cc) {
        const float* p = min_ + (size_t)(c0 + cc) * HW;
        float acc = 0.f;
        #pragma unroll
        for (int di = 0; di < ND; ++di) {
            int kb = di * 8;
            acc += p[rm[di] + cm[di]] * a[kb + 0];
            acc += p[rm[di] + x     ] * a[kb + 1];
            acc += p[rm[di] + cp[di]] * a[kb + 2];
            acc += p[yc     + cm[di]] * a[kb + 3];
            acc += p[yc     + cp[di]] * a[kb + 4];
            acc += p[rp[di] + cm[di]] * a[kb + 5];
            acc += p[rp[di] + x     ] * a[kb + 6];
            acc += p[rp[di] + cp[di]] * a[kb + 7];
        }
        if (cc == 0) acc0 = acc; else if (cc == 1) acc1 = acc; else acc2 = acc;
    }
    mout[(size_t)(c0 + 0) * HW + t] = acc0;
    mout[(size_t)(c0 + 1) * HW + t] = acc1;
    mout[(size_t)(c0 + 2) * HW + t] = acc2;
}

extern "C" void kernel_launch(void* const* d_in, const int* in_sizes, int n_in,
                              void* d_out, int out_size, void* d_ws, size_t ws_size,
                              hipStream_t stream) {
    const float* imgs  = (const float*)d_in[0];
    const float* masks = (const float*)d_in[1];
    float* out = (float*)d_out;

    float* ws = (float*)d_ws;
    float* imgs2 = ws;                       // CI*HW2 = 13467 -> pad to 16384
    float* aff2  = imgs2 + 16384;            // HW2*K  = 215472 (layout [HW2][K])
    float* afft  = aff2 + K * HW2;           // HW*K   = 2408448 (layout [HW][K])
    float* mA    = afft + (size_t)K * HW;    // CM*HW  = 1053696
    float* mB    = mA + (size_t)CM * HW;     // CM*HW  = 1053696

    // host-side positional softmax (input-independent, same every call)
    PosArr pos;
    {
        double pv[K];
        const int dil[ND] = {1, 2, 4, 8, 12, 24};
        const double s2 = sqrt(2.0);
        for (int di = 0; di < ND; ++di)
            for (int o = 0; o < 8; ++o) {
                double base = (o == 0 || o == 2 || o == 5 || o == 7) ? s2 : 1.0;
                pv[di * 8 + o] = base * (double)dil[di];
            }
        double sum = 0.0; for (int k = 0; k < K; ++k) sum += pv[k];
        double mean = sum / K;
        double ssd = 0.0; for (int k = 0; k < K; ++k) { double d0 = pv[k] - mean; ssd += d0 * d0; }
        double stdv = sqrt(ssd / (K - 1));
        double pa[K];
        double mx = -1e300;
        for (int k = 0; k < K; ++k) {
            double u = pv[k] / (stdv + 1e-8) / 0.3;
            pa[k] = -u * u;
            if (pa[k] > mx) mx = pa[k];
        }
        double es = 0.0, ev[K];
        for (int k = 0; k < K; ++k) { ev[k] = exp(pa[k] - mx); es += ev[k]; }
        for (int k = 0; k < K; ++k) pos.v[k] = (float)(ev[k] / es);
    }

    dim3 blk(256);
    k_img_down<<<(CI * HW2 + 255) / 256, blk, 0, stream>>>(imgs, imgs2);
    k_aff2<<<(HW2 * 64 + 255) / 256, blk, 0, stream>>>(imgs2, aff2);
    k_aff_total<<<(HW + 255) / 256, blk, 0, stream>>>(imgs, aff2, afft, pos);
    k_mask_up<<<(CM * HW + 255) / 256, blk, 0, stream>>>(masks, mA);

    float* bufs[2] = {mA, mB};
    const float* cur = mA;
    for (int i = 0; i < 10; ++i) {
        float* o = (i == 9) ? out : bufs[(i + 1) & 1];
        k_prop<<<PROP_TILES, dim3(448), 0, stream>>>(cur, afft, o);
        cur = o;
    }
}

// Round 4
// 312.599 us; speedup vs baseline: 1.8657x; 1.0092x over previous
//
#include <hip/hip_runtime.h>
#include <math.h>

namespace {
constexpr int IH = 224, IW = 224;
constexpr int H2 = 67, W2 = 67;
constexpr int MH = 56, MW = 56;
constexpr int CI = 3, CM = 21;
constexpr int ND = 6;
constexpr int K = 48;
constexpr int HW = IH * IW;    // 50176
constexpr int HW2 = H2 * W2;   // 4489
constexpr float EPS = 1e-8f;
constexpr int TILE = 49;                      // 49-px tiles: 1024 blocks = 4/CU uniform
constexpr int NTILES = HW / TILE;             // 1024
__device__ __constant__ int DILS_C[ND] = {1, 2, 4, 8, 12, 24};
}

__device__ __forceinline__ float wsum(float v) {
    #pragma unroll
    for (int off = 1; off < 64; off <<= 1) v += __shfl_xor(v, off);
    return v;
}
__device__ __forceinline__ float wmax(float v) {
    #pragma unroll
    for (int off = 1; off < 64; off <<= 1) v = fmaxf(v, __shfl_xor(v, off));
    return v;
}

// ---------------- bilinear downsample imgs 224->67 (align_corners) ----------
__global__ void k_img_down(const float* __restrict__ img, float* __restrict__ img2) {
    int t = blockIdx.x * blockDim.x + threadIdx.x;
    if (t >= CI * HW2) return;
    int c = t / HW2, r = t % HW2;
    int y = r / W2, x = r % W2;
    float fy = (float)y * ((float)(IH - 1) / (float)(H2 - 1));
    float fx = (float)x * ((float)(IW - 1) / (float)(W2 - 1));
    int y0 = (int)floorf(fy); int y1 = min(y0 + 1, IH - 1); float wy = fy - (float)y0;
    int x0 = (int)floorf(fx); int x1 = min(x0 + 1, IW - 1); float wx = fx - (float)x0;
    const float* p = img + c * HW;
    float v00 = p[y0 * IW + x0], v01 = p[y0 * IW + x1];
    float v10 = p[y1 * IW + x0], v11 = p[y1 * IW + x1];
    float r0 = v00 * (1.f - wy) + v10 * wy;
    float r1 = v01 * (1.f - wy) + v11 * wy;
    img2[t] = r0 * (1.f - wx) + r1 * wx;
}

// ---------------- low-res affinity: one WAVE per pixel ----------------------
// aff2 layout [HW2][K]; stores sum over channels of (|n-center|/std)^2
__global__ void k_aff2(const float* __restrict__ img2, float* __restrict__ aff2) {
    int gtid = blockIdx.x * blockDim.x + threadIdx.x;
    int wave = gtid >> 6;
    int lane = threadIdx.x & 63;
    if (wave >= HW2) return;
    int t = wave;
    int y = t / W2, x = t % W2;

    int k = (lane < K) ? lane : (K - 1);
    int di = k >> 3, o = k & 7;
    int d = DILS_C[di];
    int ym = max(y - d, 0), yp = min(y + d, H2 - 1);
    int xm = max(x - d, 0), xp = min(x + d, W2 - 1);
    const int KI[8] = {0, 0, 0, 1, 1, 2, 2, 2};
    const int KJ[8] = {0, 1, 2, 0, 2, 0, 1, 2};
    int rows[3] = {ym, y, yp};
    int cols[3] = {xm, x, xp};
    int nidx = rows[KI[o]] * W2 + cols[KJ[o]];

    float av = 0.f;
    #pragma unroll
    for (int c = 0; c < CI; ++c) {
        const float* p = img2 + c * HW2;
        float center = p[y * W2 + x];
        float v = p[nidx];
        float vv = (lane < K) ? v : 0.f;
        float s = wsum(vv);
        float s2 = wsum(vv * vv);
        float mean = s * (1.f / (float)K);
        float ss = s2 - (float)K * mean * mean;
        float stdv = sqrtf(fmaxf(ss, 0.f) * (1.f / (float)(K - 1)));
        float inv = 1.f / (stdv + EPS);
        float tt = fabsf(v - center) * inv;
        av += tt * tt;
    }
    if (lane < K) aff2[(size_t)t * K + k] = av;
}

// ---------------- full-res aff + upsampled aff2 + pos -> aff_total ----------
// one WAVE per pixel; aff2 layout [HW2][K]; writes afft[t*K + k]
__global__ void k_aff_total(const float* __restrict__ img,
                            const float* __restrict__ aff2,
                            float* __restrict__ afft) {
    int gtid = blockIdx.x * blockDim.x + threadIdx.x;
    int t = gtid >> 6;
    int lane = threadIdx.x & 63;
    if (t >= HW) return;
    int y = t / IW, x = t % IW;
    bool act = lane < K;
    int k = act ? lane : (K - 1);
    int di = k >> 3, o = k & 7;
    int d = DILS_C[di];
    const int KI[8] = {0, 0, 0, 1, 1, 2, 2, 2};
    const int KJ[8] = {0, 1, 2, 0, 2, 0, 1, 2};
    int ym = max(y - d, 0), yp = min(y + d, IH - 1);
    int xm = max(x - d, 0), xp = min(x + d, IW - 1);
    int rows[3] = {ym, y, yp};
    int cols[3] = {xm, x, xp};
    int nidx = rows[KI[o]] * IW + cols[KJ[o]];

    // full-res affinity accumulated over channels
    float av = 0.f;
    #pragma unroll
    for (int c = 0; c < CI; ++c) {
        const float* p = img + c * HW;
        float center = p[y * IW + x];
        float v = p[nidx];
        float vv = act ? v : 0.f;
        float s = wsum(vv);
        float s2 = wsum(vv * vv);
        float mean = s * (1.f / (float)K);
        float ss = s2 - (float)K * mean * mean;
        float stdv = sqrtf(fmaxf(ss, 0.f) * (1.f / (float)(K - 1)));
        float inv = 1.f / (stdv + EPS);
        float tt = fabsf(v - center) * inv;
        av += tt * tt;
    }
    av *= -(1.f / (float)CI) / (0.3f * 0.3f);
    float m1 = wmax(act ? av : -INFINITY);
    float ex1 = act ? expf(av - m1) : 0.f;
    float p1 = ex1 / wsum(ex1);

    // bilinear sample of aff2 (67x67 -> 224x224, align_corners), then softmax
    float fy = (float)y * ((float)(H2 - 1) / (float)(IH - 1));
    float fx = (float)x * ((float)(W2 - 1) / (float)(IW - 1));
    int y0 = (int)floorf(fy); int y1 = min(y0 + 1, H2 - 1); float wy = fy - (float)y0;
    int x0 = (int)floorf(fx); int x1 = min(x0 + 1, W2 - 1); float wx = fx - (float)x0;
    const float* q00 = aff2 + (size_t)(y0 * W2 + x0) * K;
    const float* q01 = aff2 + (size_t)(y0 * W2 + x1) * K;
    const float* q10 = aff2 + (size_t)(y1 * W2 + x0) * K;
    const float* q11 = aff2 + (size_t)(y1 * W2 + x1) * K;
    float w00 = (1.f - wy) * (1.f - wx), w01 = (1.f - wy) * wx;
    float w10 = wy * (1.f - wx), w11 = wy * wx;
    float v2 = (q00[k] * w00 + q01[k] * w01 + q10[k] * w10 + q11[k] * w11)
               * (-(1.f / (float)CI));
    float m2 = wmax(act ? v2 : -INFINITY);
    float ex2 = act ? expf(v2 - m2) : 0.f;
    float p2 = ex2 / wsum(ex2);

    // positional softmax computed in-wave (closed form)
    float base = (o == 0 || o == 2 || o == 5 || o == 7) ? 1.41421356237f : 1.f;
    float pv = base * (float)d;
    float pvv = act ? pv : 0.f;
    float ps = wsum(pvv);
    float ps2 = wsum(pvv * pvv);
    float pmean = ps * (1.f / (float)K);
    float pss = ps2 - (float)K * pmean * pmean;
    float pstd = sqrtf(fmaxf(pss, 0.f) * (1.f / (float)(K - 1)));
    float pu = pv / (pstd + 1e-8f) / 0.3f;
    float pa = -pu * pu;
    float pm = wmax(act ? pa : -INFINITY);
    float pe = act ? expf(pa - pm) : 0.f;
    float p3 = pe / wsum(pe);

    if (act) afft[(size_t)t * K + k] = p1 + p2 + p3;
}

// ---------------- mask upsample 56 -> 224 -----------------------------------
__global__ void k_mask_up(const float* __restrict__ m, float* __restrict__ mu) {
    int t = blockIdx.x * blockDim.x + threadIdx.x;
    if (t >= CM * HW) return;
    int c = t / HW, r = t % HW;
    int y = r / IW, x = r % IW;
    float fy = (float)y * ((float)(MH - 1) / (float)(IH - 1));
    float fx = (float)x * ((float)(MW - 1) / (float)(IW - 1));
    int y0 = (int)floorf(fy); int y1 = min(y0 + 1, MH - 1); float wy = fy - (float)y0;
    int x0 = (int)floorf(fx); int x1 = min(x0 + 1, MW - 1); float wx = fx - (float)x0;
    const float* p = m + c * MH * MW;
    float v00 = p[y0 * MW + x0], v01 = p[y0 * MW + x1];
    float v10 = p[y1 * MW + x0], v11 = p[y1 * MW + x1];
    float r0 = v00 * (1.f - wy) + v10 * wy;
    float r1 = v01 * (1.f - wy) + v11 * wy;
    mu[t] = r0 * (1.f - wx) + r1 * wx;
}

// ---------------- one propagation iteration ---------------------------------
// Block = 448 threads = 7 waves; each wave = one 3-channel group, all waves
// share the same 49-pixel tile (afft tile hits in L1 across the 7 waves).
// 1024 tiles = exactly 4 blocks/CU (uniform balance, 28 waves/CU).
__global__ __launch_bounds__(448) void k_prop(const float* __restrict__ min_,
                                              const float* __restrict__ afft,
                                              float* __restrict__ mout) {
    int w = threadIdx.x >> 6;          // 0..6 -> channel group
    int lane = threadIdx.x & 63;
    if (lane >= TILE) return;
    // bijective XCD swizzle: 1024 tiles = 8 XCDs x 128 contiguous tiles
    int bid = blockIdx.x;
    int tile = (bid & 7) * (NTILES / 8) + (bid >> 3);
    int t = tile * TILE + lane;
    int c0 = w * 3;
    int y = t / IW, x = t % IW;

    // 48 affinity weights: 12 float4 loads (afft + t*48 is 16B-aligned)
    float a[K];
    {
        const float4* af = reinterpret_cast<const float4*>(afft + (size_t)t * K);
        #pragma unroll
        for (int i = 0; i < 12; ++i) {
            float4 v = af[i];
            a[4 * i + 0] = v.x; a[4 * i + 1] = v.y;
            a[4 * i + 2] = v.z; a[4 * i + 3] = v.w;
        }
    }

    // clamped row/col offsets shared across the 3 channels
    const int DILS[ND] = {1, 2, 4, 8, 12, 24};
    int rm[ND], rp[ND], cm[ND], cp[ND];
    #pragma unroll
    for (int di = 0; di < ND; ++di) {
        int d = DILS[di];
        rm[di] = max(y - d, 0) * IW;
        rp[di] = min(y + d, IH - 1) * IW;
        cm[di] = max(x - d, 0);
        cp[di] = min(x + d, IW - 1);
    }
    int yc = y * IW;

    float acc0 = 0.f, acc1 = 0.f, acc2 = 0.f;
    #pragma unroll
    for (int cc = 0; cc < 3; ++cc) {
        const float* p = min_ + (size_t)(c0 + cc) * HW;
        float acc = 0.f;
        #pragma unroll
        for (int di = 0; di < ND; ++di) {
            int kb = di * 8;
            acc += p[rm[di] + cm[di]] * a[kb + 0];
            acc += p[rm[di] + x     ] * a[kb + 1];
            acc += p[rm[di] + cp[di]] * a[kb + 2];
            acc += p[yc     + cm[di]] * a[kb + 3];
            acc += p[yc     + cp[di]] * a[kb + 4];
            acc += p[rp[di] + cm[di]] * a[kb + 5];
            acc += p[rp[di] + x     ] * a[kb + 6];
            acc += p[rp[di] + cp[di]] * a[kb + 7];
        }
        if (cc == 0) acc0 = acc; else if (cc == 1) acc1 = acc; else acc2 = acc;
    }
    mout[(size_t)(c0 + 0) * HW + t] = acc0;
    mout[(size_t)(c0 + 1) * HW + t] = acc1;
    mout[(size_t)(c0 + 2) * HW + t] = acc2;
}

extern "C" void kernel_launch(void* const* d_in, const int* in_sizes, int n_in,
                              void* d_out, int out_size, void* d_ws, size_t ws_size,
                              hipStream_t stream) {
    const float* imgs  = (const float*)d_in[0];
    const float* masks = (const float*)d_in[1];
    float* out = (float*)d_out;

    float* ws = (float*)d_ws;
    float* imgs2 = ws;                       // CI*HW2 = 13467 -> pad to 16384
    float* aff2  = imgs2 + 16384;            // HW2*K  = 215472 (layout [HW2][K])
    float* afft  = aff2 + K * HW2;           // HW*K   = 2408448 (layout [HW][K])
    float* mA    = afft + (size_t)K * HW;    // CM*HW  = 1053696
    float* mB    = mA + (size_t)CM * HW;     // CM*HW  = 1053696

    dim3 blk(256);
    k_img_down<<<(CI * HW2 + 255) / 256, blk, 0, stream>>>(imgs, imgs2);
    k_aff2<<<(HW2 * 64 + 255) / 256, blk, 0, stream>>>(imgs2, aff2);
    k_aff_total<<<(HW * 64 + 255) / 256, blk, 0, stream>>>(imgs, aff2, afft);
    k_mask_up<<<(CM * HW + 255) / 256, blk, 0, stream>>>(masks, mA);

    float* bufs[2] = {mA, mB};
    const float* cur = mA;
    for (int i = 0; i < 10; ++i) {
        float* o = (i == 9) ? out : bufs[(i + 1) & 1];
        k_prop<<<NTILES, dim3(448), 0, stream>>>(cur, afft, o);
        cur = o;
    }
}